// Round 29
// baseline (498.158 us; speedup 1.0000x reference)
//
#include <hip/hip_runtime.h>
#include <hip/hip_bf16.h>
#include <math.h>

// ---- problem constants ----
#define CB 8
#define CT 6
#define CN 24
#define CL 1024
#define CD 512
#define CH 8
#define CDH 64
#define CTN 144     // T*N
#define CTL 6144    // T*L
#define CMS 8       // key slices in fused_bpv (768 keys each)
#define CEPS 1e-5f

typedef __bf16 bf16x8 __attribute__((ext_vector_type(8)));
typedef float  f32x4  __attribute__((ext_vector_type(4)));

#define MFMA16(a,b,c) __builtin_amdgcn_mfma_f32_16x16x32_bf16(a,b,c,0,0,0)

union BF8 { unsigned short s[8]; bf16x8 v; };

static __device__ __forceinline__ unsigned short f2bf(float x){
    union { float f; unsigned u; } c; c.f = x;
    return (unsigned short)((c.u + 0x7FFFu + ((c.u >> 16) & 1u)) >> 16);
}

static __device__ __forceinline__ float bf2f(unsigned short u){
    union { unsigned u; float f; } c; c.u = ((unsigned)u) << 16;
    return c.f;
}

static __device__ __forceinline__ bf16x8 pack8(f32x4 a, f32x4 b){
    BF8 r;
    r.s[0]=f2bf(a[0]); r.s[1]=f2bf(a[1]); r.s[2]=f2bf(a[2]); r.s[3]=f2bf(a[3]);
    r.s[4]=f2bf(b[0]); r.s[5]=f2bf(b[1]); r.s[6]=f2bf(b[2]); r.s[7]=f2bf(b[3]);
    return r.v;
}

static __device__ __forceinline__ bf16x8 ldbf8(const unsigned short* __restrict__ p){
    return *(const bf16x8*)p;
}

#define GL16(gp, lp) __builtin_amdgcn_global_load_lds((const unsigned int*)(gp), (unsigned int*)(lp), 16, 0, 0)

// ---- convert weights to bf16 ----
__global__ void cvt_w_kernel(const float* __restrict__ w0, const float* __restrict__ w1,
                             const float* __restrict__ w2, const float* __restrict__ w3,
                             unsigned short* __restrict__ o0, unsigned short* __restrict__ o1,
                             unsigned short* __restrict__ o2, unsigned short* __restrict__ o3){
    int i = blockIdx.x*blockDim.x + threadIdx.x;
    const int n = CD*CD;
    if      (i < n)   o0[i]       = f2bf(w0[i]);
    else if (i < 2*n) o1[i-n]     = f2bf(w1[i-n]);
    else if (i < 3*n) o2[i-2*n]   = f2bf(w2[i-2*n]);
    else if (i < 4*n) o3[i-3*n]   = f2bf(w3[i-3*n]);
}

// ---- pack mask into per-(t, keycol) 24-bit words ----
__global__ void maskb_kernel(const int* __restrict__ mask, unsigned int* __restrict__ maskb){
    int i = blockIdx.x*blockDim.x + threadIdx.x;   // over CT*CTL
    if (i >= CT*CTL) return;
    int t = i / CTL, m = i - t*CTL;
    unsigned w = 0;
    for (int n = 0; n < 24; ++n)
        if (mask[(size_t)(t*24 + n)*CTL + m] != 0) w |= (1u << n);
    maskb[i] = w;
}

// ---- merged k+v projection, BM=128, 4x2 wave grid: z=0 -> kp; z=1 -> vpT ----
// Wave tile 32x64, acc[2][4] (32 VGPR, same as acc[4][2]). A-fragment LDS reads
// halved vs 2x4 grid (2 col-waves share each A tile instead of 4); B (weights)
// read 4x from L2-resident 0.5 MB buffer instead of 2x -- cheap.
__global__ __launch_bounds__(512, 3) void proj_kv(
    const float* __restrict__ Xk, const float* __restrict__ Xv,
    const unsigned short* __restrict__ Wk, const unsigned short* __restrict__ Wv,
    unsigned short* __restrict__ kp, unsigned short* __restrict__ vpT)
{
    __shared__ union {
        unsigned short As[8192];   // [tile 0..7][x 0..1][lane][8 shorts], 16 KB
        float epi[32][129];
    } sm;

    int mode = blockIdx.z;         // 0=k, 1=v (block-uniform)
    const float* X = mode ? Xv : Xk;
    const unsigned short* W = mode ? Wv : Wk;

    // bijective XCD swizzle (per z-plane)
    int nwg = gridDim.x*gridDim.y;
    int id  = blockIdx.y*gridDim.x + blockIdx.x;
    int q8 = nwg >> 3, r8 = nwg & 7;
    int xcd = id & 7, rk = id >> 3;
    int swz = (xcd < r8 ? xcd*(q8+1) : r8*(q8+1) + (xcd-r8)*q8) + rk;
    int ctile = swz & 3;
    int bt    = swz >> 2;

    int tid = threadIdx.x;
    int lane = tid & 63, wave = tid >> 6;
    int wr = wave >> 1, wc = wave & 1;     // 4 row-groups x 2 col-groups
    int qq = lane & 15, g = lane >> 4;

    const float* gaf = X + (size_t)(bt*128 + wave*16 + qq)*CD + g*8;
    const unsigned short* gbw = W + (size_t)(ctile*128 + wc*64 + qq)*CD + g*8;

    f32x4 acc[2][4] = {};

    for (int k0 = 0; k0 < CD; k0 += 64) {
        #pragma unroll
        for (int x = 0; x < 2; ++x) {
            f32x4 a0 = *(const f32x4*)(gaf + k0 + x*32);
            f32x4 a1 = *(const f32x4*)(gaf + k0 + x*32 + 4);
            *(bf16x8*)(sm.As + wave*1024 + x*512 + lane*8) = pack8(a0, a1);
        }
        __syncthreads();
        #pragma unroll
        for (int x = 0; x < 2; ++x) {
            bf16x8 af[2];
            #pragma unroll
            for (int mf = 0; mf < 2; ++mf)
                af[mf] = *(const bf16x8*)&sm.As[((wr*2 + mf)*2 + x)*512 + lane*8];
            #pragma unroll
            for (int nf = 0; nf < 4; ++nf) {
                bf16x8 bw = ldbf8(gbw + (size_t)(nf*16)*CD + k0 + x*32);
                #pragma unroll
                for (int mf = 0; mf < 2; ++mf)
                    acc[mf][nf] = MFMA16(af[mf], bw, acc[mf][nf]);
            }
        }
        __syncthreads();
    }

    // epilogue: 4 passes of 32 rows via LDS; pass p served by the 2 waves with wr==p
    for (int p = 0; p < 4; ++p) {
        if (wr == p) {
            #pragma unroll
            for (int mf = 0; mf < 2; ++mf)
                #pragma unroll
                for (int nf = 0; nf < 4; ++nf)
                    #pragma unroll
                    for (int r = 0; r < 4; ++r)
                        sm.epi[mf*16 + 4*g + r][wc*64 + nf*16 + qq] = acc[mf][nf][r];
        }
        __syncthreads();
        if (mode == 1) {
            #pragma unroll
            for (int i = 0; i < 8; ++i) {
                int c2 = i*16 + wave*2 + (lane>>5);
                int gr = bt*128 + p*32 + (lane & 31);
                int bb = gr / CTL, pos = gr - bb*CTL;
                int hh = ctile*2 + (c2>>6), dh = c2 & 63;
                vpT[((size_t)(bb*CH + hh)*64 + dh)*CTL + pos] = f2bf(sm.epi[lane&31][c2]);
            }
        } else {
            #pragma unroll
            for (int i = 0; i < 8; ++i) {
                int task = i*8 + wave;
                int lr = task >> 1, ch = task & 1;
                float val = sm.epi[lr][ch*64 + lane];
                int gr = bt*128 + p*32 + lr;
                int bb = gr / CTL, pos = gr - bb*CTL;
                int hh = ctile*2 + ch;
                kp[((size_t)(bb*CH + hh)*CTL + pos)*64 + lane] = f2bf(val);
            }
        }
        __syncthreads();
    }
}

// ---- 8-wave GEMM, BK=64, fragment-major LDS (q-proj / out-proj) ----
template<int MODE, int AFMT>
__global__ __launch_bounds__(512, 4) void gemm_m97(
    const void* __restrict__ Ap, const unsigned short* __restrict__ W,
    void* __restrict__ outv, int posPer, int rowoff, float scale)
{
    __shared__ union {
        struct { unsigned short As[8192]; unsigned short Bs[8192]; } s;  // 32 KB
        float epi[32][129];
    } sm;

    int nwg = gridDim.x*gridDim.y;
    int id  = blockIdx.y*gridDim.x + blockIdx.x;
    int q8 = nwg >> 3, r8 = nwg & 7;
    int xcd = id & 7, rk = id >> 3;
    int swz = (xcd < r8 ? xcd*(q8+1) : r8*(q8+1) + (xcd-r8)*q8) + rk;
    int ctile = swz & 3;
    int bt    = swz >> 2;

    int tid = threadIdx.x;
    int lane = tid & 63, wave = tid >> 6;
    int wr = wave >> 2, wc = wave & 3;
    int qq = lane & 15, g = lane >> 4;

    const unsigned short* gah = (const unsigned short*)Ap + (size_t)(bt*128 + wave*16 + qq)*CD + g*8;
    const unsigned short* gb  = W + (size_t)(ctile*128 + wave*16 + qq)*CD + g*8;
    const float*          gaf = (const float*)Ap + (size_t)(bt*128 + wave*16 + qq)*CD + g*8;
    unsigned short* lA = sm.s.As + wave*1024;
    unsigned short* lB = sm.s.Bs + wave*1024;

    f32x4 acc[4][2] = {};

    for (int k0 = 0; k0 < CD; k0 += 64) {
        if (AFMT == 0) {
            #pragma unroll
            for (int x = 0; x < 2; ++x) {
                f32x4 a0 = *(const f32x4*)(gaf + k0 + x*32);
                f32x4 a1 = *(const f32x4*)(gaf + k0 + x*32 + 4);
                *(bf16x8*)(sm.s.As + wave*1024 + x*512 + lane*8) = pack8(a0, a1);
            }
        } else {
            GL16(gah + k0,      lA);
            GL16(gah + k0 + 32, lA + 512);
        }
        GL16(gb + k0,      lB);
        GL16(gb + k0 + 32, lB + 512);
        __syncthreads();
        #pragma unroll
        for (int x = 0; x < 2; ++x) {
            bf16x8 af[4], bf[2];
            #pragma unroll
            for (int mf = 0; mf < 4; ++mf)
                af[mf] = *(const bf16x8*)&sm.s.As[((wr*4 + mf)*2 + x)*512 + lane*8];
            #pragma unroll
            for (int nf = 0; nf < 2; ++nf)
                bf[nf] = *(const bf16x8*)&sm.s.Bs[((wc*2 + nf)*2 + x)*512 + lane*8];
            #pragma unroll
            for (int mf = 0; mf < 4; ++mf)
                #pragma unroll
                for (int nf = 0; nf < 2; ++nf)
                    acc[mf][nf] = MFMA16(af[mf], bf[nf], acc[mf][nf]);
        }
        __syncthreads();
    }

    unsigned short* outu = (unsigned short*)outv;
    float* outf = (float*)outv;
    for (int p = 0; p < 4; ++p) {
        if (wr == (p >> 1)) {
            #pragma unroll
            for (int mh = 0; mh < 2; ++mh) {
                int mf = (p&1)*2 + mh;
                #pragma unroll
                for (int nf = 0; nf < 2; ++nf)
                    #pragma unroll
                    for (int r = 0; r < 4; ++r)
                        sm.epi[mh*16 + 4*g + r][wc*32 + nf*16 + qq] = acc[mf][nf][r]*scale;
            }
        }
        __syncthreads();
        #pragma unroll
        for (int i = 0; i < 8; ++i) {
            int task = i*8 + wave;
            int lr = task >> 1, ch = task & 1;
            float val = sm.epi[lr][ch*64 + lane];
            int gr = rowoff + bt*128 + p*32 + lr;
            if (MODE == 2) {
                outf[(size_t)gr*CD + ctile*128 + ch*64 + lane] = val;
            } else {
                int bb = gr / posPer, pos = gr - bb*posPer;
                int hh = ctile*2 + ch;
                outu[((size_t)(bb*CH + hh)*posPer + pos)*64 + lane] = f2bf(val);
            }
        }
        __syncthreads();
    }
}

// ---- scores pass A: per-(b,h,t,keycol) partial max / sumexp over 24 query rows ----
__global__ __launch_bounds__(256) void scores_a_kernel(
    const unsigned short* __restrict__ qp, const unsigned short* __restrict__ kp,
    const unsigned int* __restrict__ maskb,
    float* __restrict__ pmax, float* __restrict__ psum)
{
    __shared__ float S[CTN][65];
    int mt = blockIdx.x;
    int h = blockIdx.y, b = blockIdx.z;
    int lane = threadIdx.x & 63, wave = threadIdx.x >> 6;
    const unsigned short* qbase = qp + (size_t)(b*CH + h)*CTN*64;
    const unsigned short* kbase = kp + (size_t)(b*CH + h)*CTL*64;
    int koff = 8*(lane>>4);
    f32x4 acc[3][4] = {};
    for (int k0 = 0; k0 < 64; k0 += 32) {
        bf16x8 bfr[4];
        #pragma unroll
        for (int cf = 0; cf < 4; ++cf)
            bfr[cf] = ldbf8(kbase + (size_t)(mt*64 + cf*16 + (lane&15))*64 + k0 + koff);
        #pragma unroll
        for (int i = 0; i < 3; ++i) {
            int rt = wave + 4*i;
            if (rt < 9) {
                bf16x8 a = ldbf8(qbase + (size_t)(rt*16 + (lane&15))*64 + k0 + koff);
                #pragma unroll
                for (int cf = 0; cf < 4; ++cf)
                    acc[i][cf] = MFMA16(a, bfr[cf], acc[i][cf]);
            }
        }
    }
    #pragma unroll
    for (int i = 0; i < 3; ++i) {
        int rt = wave + 4*i;
        if (rt < 9) {
            #pragma unroll
            for (int cf = 0; cf < 4; ++cf)
                #pragma unroll
                for (int r = 0; r < 4; ++r)
                    S[rt*16 + 4*(lane>>4) + r][cf*16 + (lane&15)] = acc[i][cf][r];
        }
    }
    __syncthreads();
    int mg0 = mt*64;
    for (int task = threadIdx.x; task < CT*64; task += 256) {
        int t = task >> 6, ml = task & 63;
        int mg = mg0 + ml;
        unsigned w = maskb[(size_t)t*CTL + mg];
        float mx = -INFINITY;
        float sv[24];
        #pragma unroll
        for (int i = 0; i < 24; ++i) {
            float s = ((w >> i) & 1u) ? -INFINITY : S[t*24 + i][ml];
            sv[i] = s;
            mx = fmaxf(mx, s);
        }
        float sum = 0.f;
        if (mx > -INFINITY) {
            #pragma unroll
            for (int i = 0; i < 24; ++i)
                if (sv[i] > -INFINITY) sum += __expf(sv[i] - mx);
        }
        size_t idx = ((size_t)(b*CH + h)*CT + t)*CTL + mg;
        pmax[idx] = mx; psum[idx] = sum;
    }
}

// ---- combine partial stats across heads -> stat2 = {lse, mask-bits} per (b,t,keycol) ----
__global__ void combine_kernel(const float* __restrict__ pmax, const float* __restrict__ psum,
                               const unsigned int* __restrict__ maskb,
                               float2* __restrict__ stat2){
    size_t i = (size_t)blockIdx.x*blockDim.x + threadIdx.x;
    if (i >= (size_t)CB*CT*CTL) return;
    int m = (int)(i % CTL);
    size_t bt = i / CTL;
    int t = (int)(bt % CT), b = (int)(bt / CT);
    float pm[CH], ps[CH];
    float mx = -INFINITY;
    #pragma unroll
    for (int h = 0; h < CH; ++h) {
        size_t idx = ((size_t)(b*CH + h)*CT + t)*CTL + m;
        pm[h] = pmax[idx]; ps[h] = psum[idx];
        mx = fmaxf(mx, pm[h]);
    }
    float s = 0.f;
    if (mx > -INFINITY) {
        #pragma unroll
        for (int h = 0; h < CH; ++h)
            if (pm[h] > -INFINITY) s += ps[h]*__expf(pm[h] - mx);
    }
    float lse = (mx > -INFINITY && s > 0.f) ? mx + __logf(s) : 0.f;
    float2 o; o.x = lse; o.y = __uint_as_float(maskb[(size_t)t*CTL + m]);
    stat2[i] = o;
}

// ---- fused pass B + PV: 1-wave blocks, 2 row-tiles/block; setprio on MFMA clusters ----
__global__ __launch_bounds__(64, 3) void fused_bpv(
    const unsigned short* __restrict__ qp, const unsigned short* __restrict__ kp,
    const unsigned short* __restrict__ vpT,
    const float2* __restrict__ stat2,
    float* __restrict__ avis, unsigned short* __restrict__ pvpart,
    float* __restrict__ rowpart)
{
    __shared__ unsigned short abf[16][68];
    __shared__ float av32[16][65];

    int ms = blockIdx.x;                  // CMS slices of 768 keys
    int ry = blockIdx.y;
    int bh = blockIdx.z;
    int b = bh >> 3;
    int lane = threadIdx.x;
    int qq = lane & 15, g = lane >> 4;
    int koff = 8*g;
    int nrt = (ry < 4) ? 2 : 1;
    int rt0 = ry*2;

    const unsigned short* qbase = qp + (size_t)bh*CTN*64;
    const unsigned short* kbase = kp + (size_t)bh*CTL*64;
    const unsigned short* vb    = vpT + (size_t)bh*64*CTL;

    int rbit[2];
    const float2* stp[2];
    float* avbase[2];
    bf16x8 qf[2][2];
    #pragma unroll
    for (int i = 0; i < 2; ++i) {
        int rt = rt0 + i;
        if (i >= nrt) rt = rt0;
        int qrow = rt*16 + qq;
        int t = qrow / 24;
        rbit[i] = qrow - t*24;
        stp[i] = stat2 + (size_t)(b*CT + t)*CTL;
        avbase[i] = avis + ((size_t)bh*CTN + rt*16)*CTL;
        #pragma unroll
        for (int x = 0; x < 2; ++x)
            qf[i][x] = ldbf8(qbase + (size_t)qrow*64 + x*32 + koff);
    }

    f32x4 pv[2][4] = {};
    float rs[2] = {0.f, 0.f};

    for (int mt = 0; mt < 12; ++mt) {
        int mg0 = ms*768 + mt*64;
        bf16x8 vf[2][4];
        #pragma unroll
        for (int x = 0; x < 2; ++x)
            #pragma unroll
            for (int cf = 0; cf < 4; ++cf)
                vf[x][cf] = ldbf8(vb + (size_t)(cf*16 + qq)*CTL + mg0 + x*32 + koff);
        f32x4 sacc[2][4] = {};
        __builtin_amdgcn_s_setprio(1);
        #pragma unroll
        for (int x = 0; x < 2; ++x) {
            bf16x8 kf[4];
            #pragma unroll
            for (int cf = 0; cf < 4; ++cf)
                kf[cf] = ldbf8(kbase + (size_t)(mg0 + cf*16 + qq)*64 + x*32 + koff);
            #pragma unroll
            for (int cf = 0; cf < 4; ++cf)
                sacc[0][cf] = MFMA16(kf[cf], qf[0][x], sacc[0][cf]);
            if (nrt == 2) {
                #pragma unroll
                for (int cf = 0; cf < 4; ++cf)
                    sacc[1][cf] = MFMA16(kf[cf], qf[1][x], sacc[1][cf]);
            }
        }
        __builtin_amdgcn_s_setprio(0);
        #pragma unroll
        for (int i = 0; i < 2; ++i) {
            if (i < nrt) {
                #pragma unroll
                for (int cf = 0; cf < 4; ++cf) {
                    const f32x4* sp = (const f32x4*)(stp[i] + mg0 + cf*16 + 4*g);
                    f32x4 s0 = sp[0], s1 = sp[1];
                    f32x4 av;
                    av[0] = ((__float_as_uint(s0[1]) >> rbit[i]) & 1u) ? 0.f : __expf(sacc[i][cf][0] - s0[0]);
                    av[1] = ((__float_as_uint(s0[3]) >> rbit[i]) & 1u) ? 0.f : __expf(sacc[i][cf][1] - s0[2]);
                    av[2] = ((__float_as_uint(s1[1]) >> rbit[i]) & 1u) ? 0.f : __expf(sacc[i][cf][2] - s1[0]);
                    av[3] = ((__float_as_uint(s1[3]) >> rbit[i]) & 1u) ? 0.f : __expf(sacc[i][cf][3] - s1[2]);
                    *(f32x4*)&av32[qq][cf*16 + 4*g] = av;
                    unsigned short u4[4] = { f2bf(av[0]), f2bf(av[1]), f2bf(av[2]), f2bf(av[3]) };
                    *(unsigned long long*)&abf[qq][cf*16 + 4*g] = *(unsigned long long*)u4;
                    rs[i] += av[0] + av[1] + av[2] + av[3];
                }
                #pragma unroll
                for (int p = 0; p < 4; ++p) {
                    int row = 4*p + (lane >> 4);
                    int col = 4*(lane & 15);
                    f32x4 v4 = *(const f32x4*)&av32[row][col];
                    __builtin_nontemporal_store(v4, (f32x4*)(avbase[i] + (size_t)row*CTL + mg0 + col));
                }
                __builtin_amdgcn_s_setprio(1);
                #pragma unroll
                for (int x = 0; x < 2; ++x) {
                    bf16x8 af = *(const bf16x8*)&abf[qq][x*32 + koff];
                    #pragma unroll
                    for (int cf = 0; cf < 4; ++cf)
                        pv[i][cf] = MFMA16(af, vf[x][cf], pv[i][cf]);
                }
                __builtin_amdgcn_s_setprio(0);
            }
        }
    }

    #pragma unroll
    for (int i = 0; i < 2; ++i) {
        if (i < nrt) {
            int rt = rt0 + i;
            float s = rs[i];
            s += __shfl_xor(s, 16);
            s += __shfl_xor(s, 32);
            if (g == 0)
                rowpart[(size_t)ms*(CB*CH*CTN) + (size_t)bh*CTN + rt*16 + qq] = s;
            unsigned short* pb = pvpart + ((size_t)(ms*64 + bh)*CTN + rt*16)*64;
            #pragma unroll
            for (int cf = 0; cf < 4; ++cf) {
                unsigned short u4[4] = { f2bf(pv[i][cf][0]), f2bf(pv[i][cf][1]),
                                         f2bf(pv[i][cf][2]), f2bf(pv[i][cf][3]) };
                *(unsigned long long*)&pb[cf*256 + lane*4] = *(unsigned long long*)u4;
            }
        }
    }
}

// ---- reduce PV partials + rowsums, renormalize, write oh bf16 ----
__global__ void pv_reduce_kernel(const unsigned short* __restrict__ pvpart,
                                 const float* __restrict__ rowpart,
                                 unsigned short* __restrict__ oh){
    int idx = blockIdx.x*blockDim.x + threadIdx.x;
    if (idx >= CB*CH*CTN*64) return;
    int col = idx & 63;
    int rowbh = idx >> 6;
    int row = rowbh % CTN, bh = rowbh / CTN;
    float rsum = 0.f;
    #pragma unroll
    for (int ms = 0; ms < CMS; ++ms)
        rsum += rowpart[(size_t)ms*(CB*CH*CTN) + rowbh];
    int rt = row >> 4, lr = row & 15, g = lr >> 2, r = lr & 3;
    int cf = col >> 4, qq = col & 15;
    size_t off = ((size_t)bh*CTN + rt*16)*64 + cf*256 + (g*16 + qq)*4 + r;
    float s = 0.f;
    #pragma unroll
    for (int ms = 0; ms < CMS; ++ms)
        s += bf2f(pvpart[(size_t)ms*((size_t)CB*CH*CTN*64) + off]);
    float inv = 1.f / (rsum + CEPS);
    int b = bh >> 3, h = bh & 7;
    oh[((size_t)b*CTN + row)*CD + h*64 + col] = f2bf(s*inv);
}

extern "C" void kernel_launch(void* const* d_in, const int* in_sizes, int n_in,
                              void* d_out, int out_size, void* d_ws, size_t ws_size,
                              hipStream_t stream)
{
    const float* q    = (const float*)d_in[0];
    const float* k    = (const float*)d_in[1];
    const float* v    = (const float*)d_in[2];
    const int*   mask = (const int*)  d_in[3];
    const float* Wq   = (const float*)d_in[4];
    const float* Wk   = (const float*)d_in[5];
    const float* Wv   = (const float*)d_in[6];
    const float* Wo   = (const float*)d_in[7];

    float* out0 = (float*)d_out;
    float* avis = out0 + (size_t)CB*CTN*CD;

    char* p = (char*)d_ws;
    auto alloc = [&](size_t bytes) -> char* {
        char* r = p; p += (bytes + 255) & ~(size_t)255; return r;
    };
    unsigned short* Wq_bf = (unsigned short*)alloc((size_t)CD*CD*2);
    unsigned short* Wk_bf = (unsigned short*)alloc((size_t)CD*CD*2);
    unsigned short* Wv_bf = (unsigned short*)alloc((size_t)CD*CD*2);
    unsigned short* Wo_bf = (unsigned short*)alloc((size_t)CD*CD*2);
    unsigned short* qp    = (unsigned short*)alloc((size_t)CB*CH*CTN*64*2);
    unsigned short* kp    = (unsigned short*)alloc((size_t)CB*CH*CTL*64*2);
    unsigned short* vpT   = (unsigned short*)alloc((size_t)CB*CH*64*CTL*2);
    // S region (18.87 MB), time-multiplexed:
    //   scores A:  pmax (9.44) | psum (9.44)
    //   fused_bpv: pvpart bf16 [8 slices] (9.44) aliases dead pmax/psum
    char* S = alloc((size_t)CB*CH*CT*CTL*4*2);
    float* pmax   = (float*)S;
    float* psum   = (float*)(S + (size_t)CB*CH*CT*CTL*4);
    unsigned short* pvpart = (unsigned short*)S;
    float2* stat2 = (float2*)alloc((size_t)CB*CT*CTL*8);
    unsigned int* maskb = (unsigned int*)alloc((size_t)CT*CTL*4);
    float* rowpart = (float*)alloc((size_t)CMS*CB*CH*CTN*4);
    unsigned short* oh = (unsigned short*)alloc((size_t)CB*CTN*CD*2);

    // 1. weights -> bf16; mask -> bitwords
    cvt_w_kernel<<<(4*CD*CD + 255)/256, 256, 0, stream>>>(Wq, Wk, Wv, Wo,
                                                          Wq_bf, Wk_bf, Wv_bf, Wo_bf);
    maskb_kernel<<<(CT*CTL + 255)/256, 256, 0, stream>>>(mask, maskb);
    // 2. projections: q via gemm_m97; k+v in ONE launch (z-planes, tails overlap)
    gemm_m97<0,0><<<dim3(4, CB*CTN/128), 512, 0, stream>>>(q, Wq_bf, qp, CTN, 0, 0.125f);
    proj_kv<<<dim3(4, CB*CTL/128, 2), 512, 0, stream>>>(k, v, Wk_bf, Wv_bf, kp, vpT);
    // 3. scores pass A
    scores_a_kernel<<<dim3(CTL/64, CH, CB), 256, 0, stream>>>(qp, kp, maskb, pmax, psum);
    // 4. combine across heads -> stat2 {lse, mask}
    combine_kernel<<<((CB*CT*CTL) + 255)/256, 256, 0, stream>>>(pmax, psum, maskb, stat2);
    // 5. fused pass B + PV (1-wave blocks, 2 row-tiles/block, setprio MFMA)
    fused_bpv<<<dim3(CMS, 5, CB*CH), 64, 0, stream>>>(qp, kp, vpT, stat2,
                                                      avis, pvpart, rowpart);
    // 6. reduce PV partials (+rowsum) and renormalize
    pv_reduce_kernel<<<((CB*CH*CTN*64) + 255)/256, 256, 0, stream>>>(pvpart, rowpart, oh);
    // 7. output projection (bf16 A via GL16)
    gemm_m97<2,1><<<dim3(4, CB*CTN/128), 512, 0, stream>>>(oh, Wo_bf, out0, CD, 0, 1.0f);
}

// Round 30
// 406.463 us; speedup vs baseline: 1.2256x; 1.2256x over previous
//
#include <hip/hip_runtime.h>
#include <hip/hip_bf16.h>
#include <math.h>

// ---- problem constants ----
#define CB 8
#define CT 6
#define CN 24
#define CL 1024
#define CD 512
#define CH 8
#define CDH 64
#define CTN 144     // T*N
#define CTL 6144    // T*L
#define CMS 8       // key slices in fused_bpv (768 keys each)
#define CEPS 1e-5f

typedef __bf16 bf16x8 __attribute__((ext_vector_type(8)));
typedef float  f32x4  __attribute__((ext_vector_type(4)));

#define MFMA16(a,b,c) __builtin_amdgcn_mfma_f32_16x16x32_bf16(a,b,c,0,0,0)

union BF8 { unsigned short s[8]; bf16x8 v; };

static __device__ __forceinline__ unsigned short f2bf(float x){
    union { float f; unsigned u; } c; c.f = x;
    return (unsigned short)((c.u + 0x7FFFu + ((c.u >> 16) & 1u)) >> 16);
}

static __device__ __forceinline__ float bf2f(unsigned short u){
    union { unsigned u; float f; } c; c.u = ((unsigned)u) << 16;
    return c.f;
}

static __device__ __forceinline__ bf16x8 pack8(f32x4 a, f32x4 b){
    BF8 r;
    r.s[0]=f2bf(a[0]); r.s[1]=f2bf(a[1]); r.s[2]=f2bf(a[2]); r.s[3]=f2bf(a[3]);
    r.s[4]=f2bf(b[0]); r.s[5]=f2bf(b[1]); r.s[6]=f2bf(b[2]); r.s[7]=f2bf(b[3]);
    return r.v;
}

static __device__ __forceinline__ bf16x8 ldbf8(const unsigned short* __restrict__ p){
    return *(const bf16x8*)p;
}

#define GL16(gp, lp) __builtin_amdgcn_global_load_lds((const unsigned int*)(gp), (unsigned int*)(lp), 16, 0, 0)

// ---- convert weights to bf16 ----
__global__ void cvt_w_kernel(const float* __restrict__ w0, const float* __restrict__ w1,
                             const float* __restrict__ w2, const float* __restrict__ w3,
                             unsigned short* __restrict__ o0, unsigned short* __restrict__ o1,
                             unsigned short* __restrict__ o2, unsigned short* __restrict__ o3){
    int i = blockIdx.x*blockDim.x + threadIdx.x;
    const int n = CD*CD;
    if      (i < n)   o0[i]       = f2bf(w0[i]);
    else if (i < 2*n) o1[i-n]     = f2bf(w1[i-n]);
    else if (i < 3*n) o2[i-2*n]   = f2bf(w2[i-2*n]);
    else if (i < 4*n) o3[i-3*n]   = f2bf(w3[i-3*n]);
}

// ---- pack mask into per-(t, keycol) 24-bit words ----
__global__ void maskb_kernel(const int* __restrict__ mask, unsigned int* __restrict__ maskb){
    int i = blockIdx.x*blockDim.x + threadIdx.x;   // over CT*CTL
    if (i >= CT*CTL) return;
    int t = i / CTL, m = i - t*CTL;
    unsigned w = 0;
    for (int n = 0; n < 24; ++n)
        if (mask[(size_t)(t*24 + n)*CTL + m] != 0) w |= (1u << n);
    maskb[i] = w;
}

// ---- merged k+v projection, BM=128, 2x4 wave grid (R28-proven optimum) ----
// z=0 -> kp from (k,Wk); z=1 -> vpT from (v,Wv). B-from-global, A-only LDS (16 KB).
__global__ __launch_bounds__(512, 3) void proj_kv(
    const float* __restrict__ Xk, const float* __restrict__ Xv,
    const unsigned short* __restrict__ Wk, const unsigned short* __restrict__ Wv,
    unsigned short* __restrict__ kp, unsigned short* __restrict__ vpT)
{
    __shared__ union {
        unsigned short As[8192];   // [tile 0..7][x 0..1][lane][8 shorts], 16 KB
        float epi[32][129];
    } sm;

    int mode = blockIdx.z;         // 0=k, 1=v (block-uniform)
    const float* X = mode ? Xv : Xk;
    const unsigned short* W = mode ? Wv : Wk;

    // bijective XCD swizzle (per z-plane)
    int nwg = gridDim.x*gridDim.y;
    int id  = blockIdx.y*gridDim.x + blockIdx.x;
    int q8 = nwg >> 3, r8 = nwg & 7;
    int xcd = id & 7, rk = id >> 3;
    int swz = (xcd < r8 ? xcd*(q8+1) : r8*(q8+1) + (xcd-r8)*q8) + rk;
    int ctile = swz & 3;
    int bt    = swz >> 2;

    int tid = threadIdx.x;
    int lane = tid & 63, wave = tid >> 6;
    int wr = wave >> 2, wc = wave & 3;
    int qq = lane & 15, g = lane >> 4;

    const float* gaf = X + (size_t)(bt*128 + wave*16 + qq)*CD + g*8;
    const unsigned short* gbw = W + (size_t)(ctile*128 + wc*32 + qq)*CD + g*8;

    f32x4 acc[4][2] = {};

    for (int k0 = 0; k0 < CD; k0 += 64) {
        #pragma unroll
        for (int x = 0; x < 2; ++x) {
            f32x4 a0 = *(const f32x4*)(gaf + k0 + x*32);
            f32x4 a1 = *(const f32x4*)(gaf + k0 + x*32 + 4);
            *(bf16x8*)(sm.As + wave*1024 + x*512 + lane*8) = pack8(a0, a1);
        }
        __syncthreads();
        #pragma unroll
        for (int x = 0; x < 2; ++x) {
            bf16x8 af[4];
            #pragma unroll
            for (int mf = 0; mf < 4; ++mf)
                af[mf] = *(const bf16x8*)&sm.As[((wr*4 + mf)*2 + x)*512 + lane*8];
            #pragma unroll
            for (int nf = 0; nf < 2; ++nf) {
                bf16x8 bw = ldbf8(gbw + (size_t)(nf*16)*CD + k0 + x*32);
                #pragma unroll
                for (int mf = 0; mf < 4; ++mf)
                    acc[mf][nf] = MFMA16(af[mf], bw, acc[mf][nf]);
            }
        }
        __syncthreads();
    }

    // epilogue: 4 passes of 32 rows via LDS
    for (int p = 0; p < 4; ++p) {
        if (wr == (p >> 1)) {
            #pragma unroll
            for (int mh = 0; mh < 2; ++mh) {
                int mf = (p&1)*2 + mh;
                #pragma unroll
                for (int nf = 0; nf < 2; ++nf)
                    #pragma unroll
                    for (int r = 0; r < 4; ++r)
                        sm.epi[mh*16 + 4*g + r][wc*32 + nf*16 + qq] = acc[mf][nf][r];
            }
        }
        __syncthreads();
        if (mode == 1) {
            #pragma unroll
            for (int i = 0; i < 8; ++i) {
                int c2 = i*16 + wave*2 + (lane>>5);
                int gr = bt*128 + p*32 + (lane & 31);
                int bb = gr / CTL, pos = gr - bb*CTL;
                int hh = ctile*2 + (c2>>6), dh = c2 & 63;
                vpT[((size_t)(bb*CH + hh)*64 + dh)*CTL + pos] = f2bf(sm.epi[lane&31][c2]);
            }
        } else {
            #pragma unroll
            for (int i = 0; i < 8; ++i) {
                int task = i*8 + wave;
                int lr = task >> 1, ch = task & 1;
                float val = sm.epi[lr][ch*64 + lane];
                int gr = bt*128 + p*32 + lr;
                int bb = gr / CTL, pos = gr - bb*CTL;
                int hh = ctile*2 + ch;
                kp[((size_t)(bb*CH + hh)*CTL + pos)*64 + lane] = f2bf(val);
            }
        }
        __syncthreads();
    }
}

// ---- 8-wave GEMM, BK=64, fragment-major LDS (q-proj / out-proj) ----
template<int MODE, int AFMT>
__global__ __launch_bounds__(512, 4) void gemm_m97(
    const void* __restrict__ Ap, const unsigned short* __restrict__ W,
    void* __restrict__ outv, int posPer, int rowoff, float scale)
{
    __shared__ union {
        struct { unsigned short As[8192]; unsigned short Bs[8192]; } s;  // 32 KB
        float epi[32][129];
    } sm;

    int nwg = gridDim.x*gridDim.y;
    int id  = blockIdx.y*gridDim.x + blockIdx.x;
    int q8 = nwg >> 3, r8 = nwg & 7;
    int xcd = id & 7, rk = id >> 3;
    int swz = (xcd < r8 ? xcd*(q8+1) : r8*(q8+1) + (xcd-r8)*q8) + rk;
    int ctile = swz & 3;
    int bt    = swz >> 2;

    int tid = threadIdx.x;
    int lane = tid & 63, wave = tid >> 6;
    int wr = wave >> 2, wc = wave & 3;
    int qq = lane & 15, g = lane >> 4;

    const unsigned short* gah = (const unsigned short*)Ap + (size_t)(bt*128 + wave*16 + qq)*CD + g*8;
    const unsigned short* gb  = W + (size_t)(ctile*128 + wave*16 + qq)*CD + g*8;
    const float*          gaf = (const float*)Ap + (size_t)(bt*128 + wave*16 + qq)*CD + g*8;
    unsigned short* lA = sm.s.As + wave*1024;
    unsigned short* lB = sm.s.Bs + wave*1024;

    f32x4 acc[4][2] = {};

    for (int k0 = 0; k0 < CD; k0 += 64) {
        if (AFMT == 0) {
            #pragma unroll
            for (int x = 0; x < 2; ++x) {
                f32x4 a0 = *(const f32x4*)(gaf + k0 + x*32);
                f32x4 a1 = *(const f32x4*)(gaf + k0 + x*32 + 4);
                *(bf16x8*)(sm.s.As + wave*1024 + x*512 + lane*8) = pack8(a0, a1);
            }
        } else {
            GL16(gah + k0,      lA);
            GL16(gah + k0 + 32, lA + 512);
        }
        GL16(gb + k0,      lB);
        GL16(gb + k0 + 32, lB + 512);
        __syncthreads();
        #pragma unroll
        for (int x = 0; x < 2; ++x) {
            bf16x8 af[4], bf[2];
            #pragma unroll
            for (int mf = 0; mf < 4; ++mf)
                af[mf] = *(const bf16x8*)&sm.s.As[((wr*4 + mf)*2 + x)*512 + lane*8];
            #pragma unroll
            for (int nf = 0; nf < 2; ++nf)
                bf[nf] = *(const bf16x8*)&sm.s.Bs[((wc*2 + nf)*2 + x)*512 + lane*8];
            #pragma unroll
            for (int mf = 0; mf < 4; ++mf)
                #pragma unroll
                for (int nf = 0; nf < 2; ++nf)
                    acc[mf][nf] = MFMA16(af[mf], bf[nf], acc[mf][nf]);
        }
        __syncthreads();
    }

    unsigned short* outu = (unsigned short*)outv;
    float* outf = (float*)outv;
    for (int p = 0; p < 4; ++p) {
        if (wr == (p >> 1)) {
            #pragma unroll
            for (int mh = 0; mh < 2; ++mh) {
                int mf = (p&1)*2 + mh;
                #pragma unroll
                for (int nf = 0; nf < 2; ++nf)
                    #pragma unroll
                    for (int r = 0; r < 4; ++r)
                        sm.epi[mh*16 + 4*g + r][wc*32 + nf*16 + qq] = acc[mf][nf][r]*scale;
            }
        }
        __syncthreads();
        #pragma unroll
        for (int i = 0; i < 8; ++i) {
            int task = i*8 + wave;
            int lr = task >> 1, ch = task & 1;
            float val = sm.epi[lr][ch*64 + lane];
            int gr = rowoff + bt*128 + p*32 + lr;
            if (MODE == 2) {
                outf[(size_t)gr*CD + ctile*128 + ch*64 + lane] = val;
            } else {
                int bb = gr / posPer, pos = gr - bb*posPer;
                int hh = ctile*2 + ch;
                outu[((size_t)(bb*CH + hh)*posPer + pos)*64 + lane] = f2bf(val);
            }
        }
        __syncthreads();
    }
}

// ---- scores pass A: per-(b,h,t,keycol) partial max / sumexp over 24 query rows ----
__global__ __launch_bounds__(256) void scores_a_kernel(
    const unsigned short* __restrict__ qp, const unsigned short* __restrict__ kp,
    const unsigned int* __restrict__ maskb,
    float* __restrict__ pmax, float* __restrict__ psum)
{
    __shared__ float S[CTN][65];
    int mt = blockIdx.x;
    int h = blockIdx.y, b = blockIdx.z;
    int lane = threadIdx.x & 63, wave = threadIdx.x >> 6;
    const unsigned short* qbase = qp + (size_t)(b*CH + h)*CTN*64;
    const unsigned short* kbase = kp + (size_t)(b*CH + h)*CTL*64;
    int koff = 8*(lane>>4);
    f32x4 acc[3][4] = {};
    for (int k0 = 0; k0 < 64; k0 += 32) {
        bf16x8 bfr[4];
        #pragma unroll
        for (int cf = 0; cf < 4; ++cf)
            bfr[cf] = ldbf8(kbase + (size_t)(mt*64 + cf*16 + (lane&15))*64 + k0 + koff);
        #pragma unroll
        for (int i = 0; i < 3; ++i) {
            int rt = wave + 4*i;
            if (rt < 9) {
                bf16x8 a = ldbf8(qbase + (size_t)(rt*16 + (lane&15))*64 + k0 + koff);
                #pragma unroll
                for (int cf = 0; cf < 4; ++cf)
                    acc[i][cf] = MFMA16(a, bfr[cf], acc[i][cf]);
            }
        }
    }
    #pragma unroll
    for (int i = 0; i < 3; ++i) {
        int rt = wave + 4*i;
        if (rt < 9) {
            #pragma unroll
            for (int cf = 0; cf < 4; ++cf)
                #pragma unroll
                for (int r = 0; r < 4; ++r)
                    S[rt*16 + 4*(lane>>4) + r][cf*16 + (lane&15)] = acc[i][cf][r];
        }
    }
    __syncthreads();
    int mg0 = mt*64;
    for (int task = threadIdx.x; task < CT*64; task += 256) {
        int t = task >> 6, ml = task & 63;
        int mg = mg0 + ml;
        unsigned w = maskb[(size_t)t*CTL + mg];
        float mx = -INFINITY;
        float sv[24];
        #pragma unroll
        for (int i = 0; i < 24; ++i) {
            float s = ((w >> i) & 1u) ? -INFINITY : S[t*24 + i][ml];
            sv[i] = s;
            mx = fmaxf(mx, s);
        }
        float sum = 0.f;
        if (mx > -INFINITY) {
            #pragma unroll
            for (int i = 0; i < 24; ++i)
                if (sv[i] > -INFINITY) sum += __expf(sv[i] - mx);
        }
        size_t idx = ((size_t)(b*CH + h)*CT + t)*CTL + mg;
        pmax[idx] = mx; psum[idx] = sum;
    }
}

// ---- combine partial stats across heads -> stat2 = {lse, mask-bits} per (b,t,keycol) ----
__global__ void combine_kernel(const float* __restrict__ pmax, const float* __restrict__ psum,
                               const unsigned int* __restrict__ maskb,
                               float2* __restrict__ stat2){
    size_t i = (size_t)blockIdx.x*blockDim.x + threadIdx.x;
    if (i >= (size_t)CB*CT*CTL) return;
    int m = (int)(i % CTL);
    size_t bt = i / CTL;
    int t = (int)(bt % CT), b = (int)(bt / CT);
    float pm[CH], ps[CH];
    float mx = -INFINITY;
    #pragma unroll
    for (int h = 0; h < CH; ++h) {
        size_t idx = ((size_t)(b*CH + h)*CT + t)*CTL + m;
        pm[h] = pmax[idx]; ps[h] = psum[idx];
        mx = fmaxf(mx, pm[h]);
    }
    float s = 0.f;
    if (mx > -INFINITY) {
        #pragma unroll
        for (int h = 0; h < CH; ++h)
            if (pm[h] > -INFINITY) s += ps[h]*__expf(pm[h] - mx);
    }
    float lse = (mx > -INFINITY && s > 0.f) ? mx + __logf(s) : 0.f;
    float2 o; o.x = lse; o.y = __uint_as_float(maskb[(size_t)t*CTL + m]);
    stat2[i] = o;
}

// ---- fused pass B + PV: 1-wave blocks, 2 row-tiles/block; setprio on MFMA clusters ----
__global__ __launch_bounds__(64, 3) void fused_bpv(
    const unsigned short* __restrict__ qp, const unsigned short* __restrict__ kp,
    const unsigned short* __restrict__ vpT,
    const float2* __restrict__ stat2,
    float* __restrict__ avis, unsigned short* __restrict__ pvpart,
    float* __restrict__ rowpart)
{
    __shared__ unsigned short abf[16][68];
    __shared__ float av32[16][65];

    int ms = blockIdx.x;                  // CMS slices of 768 keys
    int ry = blockIdx.y;
    int bh = blockIdx.z;
    int b = bh >> 3;
    int lane = threadIdx.x;
    int qq = lane & 15, g = lane >> 4;
    int koff = 8*g;
    int nrt = (ry < 4) ? 2 : 1;
    int rt0 = ry*2;

    const unsigned short* qbase = qp + (size_t)bh*CTN*64;
    const unsigned short* kbase = kp + (size_t)bh*CTL*64;
    const unsigned short* vb    = vpT + (size_t)bh*64*CTL;

    int rbit[2];
    const float2* stp[2];
    float* avbase[2];
    bf16x8 qf[2][2];
    #pragma unroll
    for (int i = 0; i < 2; ++i) {
        int rt = rt0 + i;
        if (i >= nrt) rt = rt0;
        int qrow = rt*16 + qq;
        int t = qrow / 24;
        rbit[i] = qrow - t*24;
        stp[i] = stat2 + (size_t)(b*CT + t)*CTL;
        avbase[i] = avis + ((size_t)bh*CTN + rt*16)*CTL;
        #pragma unroll
        for (int x = 0; x < 2; ++x)
            qf[i][x] = ldbf8(qbase + (size_t)qrow*64 + x*32 + koff);
    }

    f32x4 pv[2][4] = {};
    float rs[2] = {0.f, 0.f};

    for (int mt = 0; mt < 12; ++mt) {
        int mg0 = ms*768 + mt*64;
        bf16x8 vf[2][4];
        #pragma unroll
        for (int x = 0; x < 2; ++x)
            #pragma unroll
            for (int cf = 0; cf < 4; ++cf)
                vf[x][cf] = ldbf8(vb + (size_t)(cf*16 + qq)*CTL + mg0 + x*32 + koff);
        f32x4 sacc[2][4] = {};
        __builtin_amdgcn_s_setprio(1);
        #pragma unroll
        for (int x = 0; x < 2; ++x) {
            bf16x8 kf[4];
            #pragma unroll
            for (int cf = 0; cf < 4; ++cf)
                kf[cf] = ldbf8(kbase + (size_t)(mg0 + cf*16 + qq)*64 + x*32 + koff);
            #pragma unroll
            for (int cf = 0; cf < 4; ++cf)
                sacc[0][cf] = MFMA16(kf[cf], qf[0][x], sacc[0][cf]);
            if (nrt == 2) {
                #pragma unroll
                for (int cf = 0; cf < 4; ++cf)
                    sacc[1][cf] = MFMA16(kf[cf], qf[1][x], sacc[1][cf]);
            }
        }
        __builtin_amdgcn_s_setprio(0);
        #pragma unroll
        for (int i = 0; i < 2; ++i) {
            if (i < nrt) {
                #pragma unroll
                for (int cf = 0; cf < 4; ++cf) {
                    const f32x4* sp = (const f32x4*)(stp[i] + mg0 + cf*16 + 4*g);
                    f32x4 s0 = sp[0], s1 = sp[1];
                    f32x4 av;
                    av[0] = ((__float_as_uint(s0[1]) >> rbit[i]) & 1u) ? 0.f : __expf(sacc[i][cf][0] - s0[0]);
                    av[1] = ((__float_as_uint(s0[3]) >> rbit[i]) & 1u) ? 0.f : __expf(sacc[i][cf][1] - s0[2]);
                    av[2] = ((__float_as_uint(s1[1]) >> rbit[i]) & 1u) ? 0.f : __expf(sacc[i][cf][2] - s1[0]);
                    av[3] = ((__float_as_uint(s1[3]) >> rbit[i]) & 1u) ? 0.f : __expf(sacc[i][cf][3] - s1[2]);
                    *(f32x4*)&av32[qq][cf*16 + 4*g] = av;
                    unsigned short u4[4] = { f2bf(av[0]), f2bf(av[1]), f2bf(av[2]), f2bf(av[3]) };
                    *(unsigned long long*)&abf[qq][cf*16 + 4*g] = *(unsigned long long*)u4;
                    rs[i] += av[0] + av[1] + av[2] + av[3];
                }
                #pragma unroll
                for (int p = 0; p < 4; ++p) {
                    int row = 4*p + (lane >> 4);
                    int col = 4*(lane & 15);
                    f32x4 v4 = *(const f32x4*)&av32[row][col];
                    __builtin_nontemporal_store(v4, (f32x4*)(avbase[i] + (size_t)row*CTL + mg0 + col));
                }
                __builtin_amdgcn_s_setprio(1);
                #pragma unroll
                for (int x = 0; x < 2; ++x) {
                    bf16x8 af = *(const bf16x8*)&abf[qq][x*32 + koff];
                    #pragma unroll
                    for (int cf = 0; cf < 4; ++cf)
                        pv[i][cf] = MFMA16(af, vf[x][cf], pv[i][cf]);
                }
                __builtin_amdgcn_s_setprio(0);
            }
        }
    }

    #pragma unroll
    for (int i = 0; i < 2; ++i) {
        if (i < nrt) {
            int rt = rt0 + i;
            float s = rs[i];
            s += __shfl_xor(s, 16);
            s += __shfl_xor(s, 32);
            if (g == 0)
                rowpart[(size_t)ms*(CB*CH*CTN) + (size_t)bh*CTN + rt*16 + qq] = s;
            unsigned short* pb = pvpart + ((size_t)(ms*64 + bh)*CTN + rt*16)*64;
            #pragma unroll
            for (int cf = 0; cf < 4; ++cf) {
                unsigned short u4[4] = { f2bf(pv[i][cf][0]), f2bf(pv[i][cf][1]),
                                         f2bf(pv[i][cf][2]), f2bf(pv[i][cf][3]) };
                *(unsigned long long*)&pb[cf*256 + lane*4] = *(unsigned long long*)u4;
            }
        }
    }
}

// ---- reduce PV partials + rowsums, renormalize, write oh bf16 ----
__global__ void pv_reduce_kernel(const unsigned short* __restrict__ pvpart,
                                 const float* __restrict__ rowpart,
                                 unsigned short* __restrict__ oh){
    int idx = blockIdx.x*blockDim.x + threadIdx.x;
    if (idx >= CB*CH*CTN*64) return;
    int col = idx & 63;
    int rowbh = idx >> 6;
    int row = rowbh % CTN, bh = rowbh / CTN;
    float rsum = 0.f;
    #pragma unroll
    for (int ms = 0; ms < CMS; ++ms)
        rsum += rowpart[(size_t)ms*(CB*CH*CTN) + rowbh];
    int rt = row >> 4, lr = row & 15, g = lr >> 2, r = lr & 3;
    int cf = col >> 4, qq = col & 15;
    size_t off = ((size_t)bh*CTN + rt*16)*64 + cf*256 + (g*16 + qq)*4 + r;
    float s = 0.f;
    #pragma unroll
    for (int ms = 0; ms < CMS; ++ms)
        s += bf2f(pvpart[(size_t)ms*((size_t)CB*CH*CTN*64) + off]);
    float inv = 1.f / (rsum + CEPS);
    int b = bh >> 3, h = bh & 7;
    oh[((size_t)b*CTN + row)*CD + h*64 + col] = f2bf(s*inv);
}

extern "C" void kernel_launch(void* const* d_in, const int* in_sizes, int n_in,
                              void* d_out, int out_size, void* d_ws, size_t ws_size,
                              hipStream_t stream)
{
    const float* q    = (const float*)d_in[0];
    const float* k    = (const float*)d_in[1];
    const float* v    = (const float*)d_in[2];
    const int*   mask = (const int*)  d_in[3];
    const float* Wq   = (const float*)d_in[4];
    const float* Wk   = (const float*)d_in[5];
    const float* Wv   = (const float*)d_in[6];
    const float* Wo   = (const float*)d_in[7];

    float* out0 = (float*)d_out;
    float* avis = out0 + (size_t)CB*CTN*CD;

    char* p = (char*)d_ws;
    auto alloc = [&](size_t bytes) -> char* {
        char* r = p; p += (bytes + 255) & ~(size_t)255; return r;
    };
    unsigned short* Wq_bf = (unsigned short*)alloc((size_t)CD*CD*2);
    unsigned short* Wk_bf = (unsigned short*)alloc((size_t)CD*CD*2);
    unsigned short* Wv_bf = (unsigned short*)alloc((size_t)CD*CD*2);
    unsigned short* Wo_bf = (unsigned short*)alloc((size_t)CD*CD*2);
    unsigned short* qp    = (unsigned short*)alloc((size_t)CB*CH*CTN*64*2);
    unsigned short* kp    = (unsigned short*)alloc((size_t)CB*CH*CTL*64*2);
    unsigned short* vpT   = (unsigned short*)alloc((size_t)CB*CH*64*CTL*2);
    // S region (18.87 MB), time-multiplexed:
    //   scores A:  pmax (9.44) | psum (9.44)
    //   fused_bpv: pvpart bf16 [8 slices] (9.44) aliases dead pmax/psum
    char* S = alloc((size_t)CB*CH*CT*CTL*4*2);
    float* pmax   = (float*)S;
    float* psum   = (float*)(S + (size_t)CB*CH*CT*CTL*4);
    unsigned short* pvpart = (unsigned short*)S;
    float2* stat2 = (float2*)alloc((size_t)CB*CT*CTL*8);
    unsigned int* maskb = (unsigned int*)alloc((size_t)CT*CTL*4);
    float* rowpart = (float*)alloc((size_t)CMS*CB*CH*CTN*4);
    unsigned short* oh = (unsigned short*)alloc((size_t)CB*CTN*CD*2);

    // 1. weights -> bf16; mask -> bitwords
    cvt_w_kernel<<<(4*CD*CD + 255)/256, 256, 0, stream>>>(Wq, Wk, Wv, Wo,
                                                          Wq_bf, Wk_bf, Wv_bf, Wo_bf);
    maskb_kernel<<<(CT*CTL + 255)/256, 256, 0, stream>>>(mask, maskb);
    // 2. projections: q via gemm_m97; k+v in ONE launch (z-planes, tails overlap)
    gemm_m97<0,0><<<dim3(4, CB*CTN/128), 512, 0, stream>>>(q, Wq_bf, qp, CTN, 0, 0.125f);
    proj_kv<<<dim3(4, CB*CTL/128, 2), 512, 0, stream>>>(k, v, Wk_bf, Wv_bf, kp, vpT);
    // 3. scores pass A
    scores_a_kernel<<<dim3(CTL/64, CH, CB), 256, 0, stream>>>(qp, kp, maskb, pmax, psum);
    // 4. combine across heads -> stat2 {lse, mask}
    combine_kernel<<<((CB*CT*CTL) + 255)/256, 256, 0, stream>>>(pmax, psum, maskb, stat2);
    // 5. fused pass B + PV (1-wave blocks, 2 row-tiles/block, setprio MFMA)
    fused_bpv<<<dim3(CMS, 5, CB*CH), 64, 0, stream>>>(qp, kp, vpT, stat2,
                                                      avis, pvpart, rowpart);
    // 6. reduce PV partials (+rowsum) and renormalize
    pv_reduce_kernel<<<((CB*CH*CTN*64) + 255)/256, 256, 0, stream>>>(pvpart, rowpart, oh);
    // 7. output projection (bf16 A via GL16)
    gemm_m97<2,1><<<dim3(4, CB*CTN/128), 512, 0, stream>>>(oh, Wo_bf, out0, CD, 0, 1.0f);
}